// Round 8
// baseline (159.530 us; speedup 1.0000x reference)
//
#include <hip/hip_runtime.h>
#include <cmath>

#define N_J   44      // 4 delta + 8 theta + 32 gamma
#define KDIM  128
#define NCLS  5
#define NT    3       // n-tiles of 16 (44 padded to 48)
#define WCE_OFF (N_J * KDIM)   // ws offset of padded [48][5] classifier weights

typedef __attribute__((ext_vector_type(8))) short bf16x8;
typedef __attribute__((ext_vector_type(4))) float f32x4;

// ---------------------------------------------------------------------------
__device__ __forceinline__ float fast_tanh(float a) {
    float z = fminf(fabsf(a), 15.0f);
    float e = __expf(2.0f * z);
    float t = fmaf(-2.0f, __builtin_amdgcn_rcpf(e + 1.0f), 1.0f);
    return copysignf(t, a);
}

// round-to-nearest-even f32 -> bf16 bits (proven fast path; __float22bfloat162_rn
// measured ~20us slower across R3/R5/R6)
__device__ __forceinline__ short bf16_rne(float f) {
    unsigned u = __builtin_bit_cast(unsigned, f);
    unsigned r = (u + 0x7fffu + ((u >> 16) & 1u)) >> 16;
    return (short)r;
}

// ---------------------------------------------------------------------------
// prep: W_all^T [44][128] f32 at ws[0..5632), Wc_eff padded [48][5] (gamma
// rows scaled by C, rows 44..47 zero) at ws[5632..5872).
__global__ void hc_prep(const float* __restrict__ Wd, const float* __restrict__ Wt,
                        const float* __restrict__ Wg, const float* __restrict__ Wc,
                        float C, float* __restrict__ ws) {
    int tid = blockIdx.x * blockDim.x + threadIdx.x;
    int nthr = gridDim.x * blockDim.x;
    for (int idx = tid; idx < N_J * KDIM; idx += nthr) {
        int j = idx / KDIM, k = idx % KDIM;
        float v;
        if (j < 4)       v = Wd[k * 4  + j];
        else if (j < 12) v = Wt[k * 8  + (j - 4)];
        else             v = Wg[k * 32 + (j - 12)];
        ws[idx] = v;
    }
    for (int idx = tid; idx < 48 * NCLS; idx += nthr) {
        int j = idx / NCLS;
        float v = (j < N_J) ? Wc[idx] * (j >= 12 ? C : 1.0f) : 0.0f;
        ws[WCE_OFF + idx] = v;
    }
}

// ---------------------------------------------------------------------------
// main: 16-row tiles per wave, swapped-operand mfma(A=W^T frag, B=x frag) so
// lane (g,n) holds S[row=n][j=16t+4g+r] -> lane-local classifier + 2 shuffles.
// W frags + classifier weights live in LDS in FRAGMENT ORDER (lane-linear,
// conflict-free ds_read_b128), cutting persistent VGPRs ~108 -> ~0 and
// raising occupancy 3 -> 5 waves/SIMD.
__global__ __launch_bounds__(256, 5) void hc_main(
        const float* __restrict__ x, const float* __restrict__ ws,
        const float* __restrict__ bc, float* __restrict__ out, int nrows) {
    __shared__ short sW[NT * 4 * 64 * 8];   // [t][kb][lane] bf16x8 chunks, 12KB
    __shared__ float sWce[NCLS * NT * 4 * 4]; // [c][t][g] float4 chunks, 960B

    const int lane = threadIdx.x & 63;
    const int n    = lane & 15;        // x-row-in-tile
    const int g    = lane >> 4;        // k-group / j-subgroup
    const int wave   = (blockIdx.x * blockDim.x + threadIdx.x) >> 6;
    const int nwaves = (gridDim.x * blockDim.x) >> 6;
    const int ntiles = (nrows + 15) / 16;

    // ---- build LDS stashes (once per workgroup) ----------------------------
    for (int cid = threadIdx.x; cid < NT * 4 * 64; cid += 256) {
        const int t  = cid >> 8;
        const int kb = (cid >> 6) & 3;
        const int ln = cid & 63;
        const int jj = t * 16 + (ln & 15);
        const int gg = ln >> 4;
        float4 q0 = {0,0,0,0}, q1 = {0,0,0,0};
        if (jj < N_J) {
            const float4* wp = reinterpret_cast<const float4*>(ws + jj * KDIM + kb * 32 + gg * 8);
            q0 = wp[0]; q1 = wp[1];
        }
        bf16x8 v;
        v[0] = bf16_rne(q0.x); v[1] = bf16_rne(q0.y);
        v[2] = bf16_rne(q0.z); v[3] = bf16_rne(q0.w);
        v[4] = bf16_rne(q1.x); v[5] = bf16_rne(q1.y);
        v[6] = bf16_rne(q1.z); v[7] = bf16_rne(q1.w);
        *reinterpret_cast<bf16x8*>(&sW[cid * 8]) = v;
    }
    for (int idx = threadIdx.x; idx < NCLS * 48; idx += 256) {
        // dst layout [c][t][g][r], r fastest
        const int c = idx / 48;
        const int t = (idx >> 4) % 3;
        const int gg = (idx >> 2) & 3;
        const int r = idx & 3;
        const int j = t * 16 + gg * 4 + r;
        sWce[idx] = (j < N_J) ? ws[WCE_OFF + j * NCLS + c] : 0.0f;
    }
    __syncthreads();

    const bf16x8* __restrict__ sWf  = reinterpret_cast<const bf16x8*>(sW);
    const float4* __restrict__ wc4  = reinterpret_cast<const float4*>(sWce);

    float bcv[NCLS];
#pragma unroll
    for (int c = 0; c < NCLS; ++c) bcv[c] = bc[c];

    for (int tile = wave; tile < ntiles; tile += nwaves) {
        const int rowb = tile * 16;
        const int row  = rowb + n;
        const bool rok = (row < nrows);

        // ---- load x: this lane's 32 floats (row `row`, k = kb*32 + g*8 ..+8)
        float4 raw[8];
        const float4* xp = reinterpret_cast<const float4*>(x)
                           + (unsigned)(row * 32 + g * 2);
#pragma unroll
        for (int kb = 0; kb < 4; ++kb) {
            raw[2*kb]     = rok ? xp[kb * 8]     : float4{0,0,0,0};
            raw[2*kb + 1] = rok ? xp[kb * 8 + 1] : float4{0,0,0,0};
        }

        f32x4 acc[NT];
#pragma unroll
        for (int t = 0; t < NT; ++t) acc[t] = f32x4{0.0f, 0.0f, 0.0f, 0.0f};

#pragma unroll
        for (int kb = 0; kb < 4; ++kb) {
            float f[8] = { raw[2*kb].x, raw[2*kb].y, raw[2*kb].z, raw[2*kb].w,
                           raw[2*kb+1].x, raw[2*kb+1].y, raw[2*kb+1].z, raw[2*kb+1].w };
            bf16x8 av;
#pragma unroll
            for (int i = 0; i < 8; ++i) av[i] = bf16_rne(f[i]);
#pragma unroll
            for (int t = 0; t < NT; ++t)
                acc[t] = __builtin_amdgcn_mfma_f32_16x16x32_bf16(
                             sWf[(t * 4 + kb) * 64 + lane], av, acc[t], 0, 0, 0);
        }

        // ---- epilogue: lane-local tanh + classifier, then 2-step reduce ----
        float th[NT][4];
#pragma unroll
        for (int t = 0; t < NT; ++t)
#pragma unroll
            for (int r = 0; r < 4; ++r)
                th[t][r] = fast_tanh(acc[t][r]);

        float o[NCLS];
#pragma unroll
        for (int c = 0; c < NCLS; ++c) {
            float s = 0.0f;
#pragma unroll
            for (int t = 0; t < NT; ++t) {
                const float4 f = wc4[(c * 3 + t) * 4 + g];
                s = fmaf(th[t][0], f.x, fmaf(th[t][1], f.y,
                    fmaf(th[t][2], f.z, fmaf(th[t][3], f.w, s))));
            }
            o[c] = s;
        }
#pragma unroll
        for (int c = 0; c < NCLS; ++c) {
            o[c] += __shfl_xor(o[c], 16);
            o[c] += __shfl_xor(o[c], 32);
        }

        if (g == 0 && rok) {
#pragma unroll
            for (int c = 0; c < NCLS; ++c)
                out[(unsigned)row * NCLS + c] = o[c] + bcv[c];
        }
    }
}

// ---------------------------------------------------------------------------
extern "C" void kernel_launch(void* const* d_in, const int* in_sizes, int n_in,
                              void* d_out, int out_size, void* d_ws, size_t ws_size,
                              hipStream_t stream) {
    const float* x  = (const float*)d_in[0];
    const float* Wd = (const float*)d_in[1];
    const float* Wt = (const float*)d_in[2];
    const float* Wg = (const float*)d_in[3];
    const float* Wc = (const float*)d_in[4];
    const float* bc = (const float*)d_in[5];
    float* out = (float*)d_out;
    const int nrows = in_sizes[0] / KDIM;

    // -------- host: closed-form gamma amplitude scale C (data-independent) ---
    const double dt = 0.01, twopi = 6.283185307179586476925286766559;
    double fd[4], ft[8], pht[8];
    for (int i = 0; i < 4; ++i) fd[i] = 1.0 + 3.0 * (double)i / 3.0;   // 1..4
    for (int i = 0; i < 8; ++i) { ft[i] = 4.0 + 4.0 * (double)i / 7.0; pht[i] = 0.0; }
    double Csum = 0.0;
    for (int k = 0; k < 5; ++k) {
        double s = 0.0, c = 0.0;
        for (int i = 0; i < 4; ++i) { double p = twopi * fd[i] * dt * (double)k; s += sin(p); c += cos(p); }
        double mpd = atan2(s * 0.25, c * 0.25);
        double s2 = 0.0, c2 = 0.0;
        for (int i = 0; i < 8; ++i) { s2 += sin(pht[i]); c2 += cos(pht[i]); }
        double mpt = atan2(s2 * 0.125, c2 * 0.125);
        double pac = 1.0 + 0.3 * cos(mpt);
        Csum += pac * pow(1.0 - dt, 4.0 - (double)k);
        for (int i = 0; i < 8; ++i)
            pht[i] += dt * (twopi * ft[i] + 2.0 * sin(mpd - pht[i]));
    }
    const double Cd = pow(1.0 - dt, 5.0) + dt * Csum;
    const float C = (float)Cd;

    hc_prep<<<23, 256, 0, stream>>>(Wd, Wt, Wg, Wc, C, (float*)d_ws);
    hc_main<<<2048, 256, 0, stream>>>(x, (const float*)d_ws, bc, out, nrows);
}

// Round 9
// 100.084 us; speedup vs baseline: 1.5940x; 1.5940x over previous
//
#include <hip/hip_runtime.h>
#include <cmath>

#define N_J   44      // 4 delta + 8 theta + 32 gamma
#define KDIM  128
#define NCLS  5
#define NT    3       // n-tiles of 16 (44 padded to 48)
#define WCE_OFF (N_J * KDIM)   // ws offset of padded [48][5] classifier weights

typedef __attribute__((ext_vector_type(8))) short bf16x8;
typedef __attribute__((ext_vector_type(4))) float f32x4;

// ---------------------------------------------------------------------------
__device__ __forceinline__ float fast_tanh(float a) {
    float z = fminf(fabsf(a), 15.0f);
    float e = __expf(2.0f * z);
    float t = fmaf(-2.0f, __builtin_amdgcn_rcpf(e + 1.0f), 1.0f);
    return copysignf(t, a);
}

// round-to-nearest-even f32 -> bf16 bits (proven fast path; __float22bfloat162_rn
// measured ~20us slower across R3/R5/R6)
__device__ __forceinline__ short bf16_rne(float f) {
    unsigned u = __builtin_bit_cast(unsigned, f);
    unsigned r = (u + 0x7fffu + ((u >> 16) & 1u)) >> 16;
    return (short)r;
}

// ---------------------------------------------------------------------------
// prep: W_all^T [44][128] f32 at ws[0..5632), Wc_eff padded [48][5] (gamma
// rows scaled by C, rows 44..47 zero) at ws[5632..5872).
__global__ void hc_prep(const float* __restrict__ Wd, const float* __restrict__ Wt,
                        const float* __restrict__ Wg, const float* __restrict__ Wc,
                        float C, float* __restrict__ ws) {
    int tid = blockIdx.x * blockDim.x + threadIdx.x;
    int nthr = gridDim.x * blockDim.x;
    for (int idx = tid; idx < N_J * KDIM; idx += nthr) {
        int j = idx / KDIM, k = idx % KDIM;
        float v;
        if (j < 4)       v = Wd[k * 4  + j];
        else if (j < 12) v = Wt[k * 8  + (j - 4)];
        else             v = Wg[k * 32 + (j - 12)];
        ws[idx] = v;
    }
    for (int idx = tid; idx < 48 * NCLS; idx += nthr) {
        int j = idx / NCLS;
        float v = (j < N_J) ? Wc[idx] * (j >= 12 ? C : 1.0f) : 0.0f;
        ws[WCE_OFF + idx] = v;
    }
}

// ---------------------------------------------------------------------------
// main: 16-row tiles per wave, swapped-operand mfma(A=W^T frag, B=x frag) so
// lane (g,n) holds S[row=n][j=16t+4g+r] -> lane-local classifier + 2 shuffles.
// W frags + classifier weights in LDS in fragment order (lane-linear,
// conflict-free: SQ_LDS_BANK_CONFLICT=0 measured in R8).
// __launch_bounds__(256,4): R8's (256,5) capped VGPR at 48 -> 123MB of scratch
// spill (WRITE_SIZE 133MB vs 10MB output). 4 waves/SIMD = 128-VGPR cap fits
// the ~90-reg working set with zero spill.
__global__ __launch_bounds__(256, 4) void hc_main(
        const float* __restrict__ x, const float* __restrict__ ws,
        const float* __restrict__ bc, float* __restrict__ out, int nrows) {
    __shared__ short sW[NT * 4 * 64 * 8];     // [t][kb][lane] bf16x8 chunks, 12KB
    __shared__ float sWce[NCLS * NT * 4 * 4]; // [c][t][g][r] float4 chunks, 960B

    const int lane = threadIdx.x & 63;
    const int n    = lane & 15;        // x-row-in-tile
    const int g    = lane >> 4;        // k-group / j-subgroup
    const int wave   = (blockIdx.x * blockDim.x + threadIdx.x) >> 6;
    const int nwaves = (gridDim.x * blockDim.x) >> 6;
    const int ntiles = (nrows + 15) / 16;

    // ---- build LDS stashes (once per workgroup) ----------------------------
    for (int cid = threadIdx.x; cid < NT * 4 * 64; cid += 256) {
        const int t  = cid >> 8;
        const int kb = (cid >> 6) & 3;
        const int ln = cid & 63;
        const int jj = t * 16 + (ln & 15);
        const int gg = ln >> 4;
        float4 q0 = {0,0,0,0}, q1 = {0,0,0,0};
        if (jj < N_J) {
            const float4* wp = reinterpret_cast<const float4*>(ws + jj * KDIM + kb * 32 + gg * 8);
            q0 = wp[0]; q1 = wp[1];
        }
        bf16x8 v;
        v[0] = bf16_rne(q0.x); v[1] = bf16_rne(q0.y);
        v[2] = bf16_rne(q0.z); v[3] = bf16_rne(q0.w);
        v[4] = bf16_rne(q1.x); v[5] = bf16_rne(q1.y);
        v[6] = bf16_rne(q1.z); v[7] = bf16_rne(q1.w);
        *reinterpret_cast<bf16x8*>(&sW[cid * 8]) = v;
    }
    for (int idx = threadIdx.x; idx < NCLS * 48; idx += 256) {
        // dst layout [c][t][g][r], r fastest
        const int c = idx / 48;
        const int t = (idx >> 4) % 3;
        const int gg = (idx >> 2) & 3;
        const int r = idx & 3;
        const int j = t * 16 + gg * 4 + r;
        sWce[idx] = (j < N_J) ? ws[WCE_OFF + j * NCLS + c] : 0.0f;
    }
    __syncthreads();

    const bf16x8* __restrict__ sWf  = reinterpret_cast<const bf16x8*>(sW);
    const float4* __restrict__ wc4  = reinterpret_cast<const float4*>(sWce);

    float bcv[NCLS];
#pragma unroll
    for (int c = 0; c < NCLS; ++c) bcv[c] = bc[c];

    for (int tile = wave; tile < ntiles; tile += nwaves) {
        const int rowb = tile * 16;
        const int row  = rowb + n;
        const bool rok = (row < nrows);

        // ---- load x: this lane's 32 floats (row `row`, k = kb*32 + g*8 ..+8)
        float4 raw[8];
        const float4* xp = reinterpret_cast<const float4*>(x)
                           + (unsigned)(row * 32 + g * 2);
#pragma unroll
        for (int kb = 0; kb < 4; ++kb) {
            raw[2*kb]     = rok ? xp[kb * 8]     : float4{0,0,0,0};
            raw[2*kb + 1] = rok ? xp[kb * 8 + 1] : float4{0,0,0,0};
        }

        f32x4 acc[NT];
#pragma unroll
        for (int t = 0; t < NT; ++t) acc[t] = f32x4{0.0f, 0.0f, 0.0f, 0.0f};

#pragma unroll
        for (int kb = 0; kb < 4; ++kb) {
            float f[8] = { raw[2*kb].x, raw[2*kb].y, raw[2*kb].z, raw[2*kb].w,
                           raw[2*kb+1].x, raw[2*kb+1].y, raw[2*kb+1].z, raw[2*kb+1].w };
            bf16x8 av;
#pragma unroll
            for (int i = 0; i < 8; ++i) av[i] = bf16_rne(f[i]);
#pragma unroll
            for (int t = 0; t < NT; ++t)
                acc[t] = __builtin_amdgcn_mfma_f32_16x16x32_bf16(
                             sWf[(t * 4 + kb) * 64 + lane], av, acc[t], 0, 0, 0);
        }

        // ---- epilogue: lane-local tanh + classifier, then 2-step reduce ----
        float th[NT][4];
#pragma unroll
        for (int t = 0; t < NT; ++t)
#pragma unroll
            for (int r = 0; r < 4; ++r)
                th[t][r] = fast_tanh(acc[t][r]);

        float o[NCLS];
#pragma unroll
        for (int c = 0; c < NCLS; ++c) {
            float s = 0.0f;
#pragma unroll
            for (int t = 0; t < NT; ++t) {
                const float4 f = wc4[(c * 3 + t) * 4 + g];
                s = fmaf(th[t][0], f.x, fmaf(th[t][1], f.y,
                    fmaf(th[t][2], f.z, fmaf(th[t][3], f.w, s))));
            }
            o[c] = s;
        }
#pragma unroll
        for (int c = 0; c < NCLS; ++c) {
            o[c] += __shfl_xor(o[c], 16);
            o[c] += __shfl_xor(o[c], 32);
        }

        if (g == 0 && rok) {
#pragma unroll
            for (int c = 0; c < NCLS; ++c)
                out[(unsigned)row * NCLS + c] = o[c] + bcv[c];
        }
    }
}

// ---------------------------------------------------------------------------
extern "C" void kernel_launch(void* const* d_in, const int* in_sizes, int n_in,
                              void* d_out, int out_size, void* d_ws, size_t ws_size,
                              hipStream_t stream) {
    const float* x  = (const float*)d_in[0];
    const float* Wd = (const float*)d_in[1];
    const float* Wt = (const float*)d_in[2];
    const float* Wg = (const float*)d_in[3];
    const float* Wc = (const float*)d_in[4];
    const float* bc = (const float*)d_in[5];
    float* out = (float*)d_out;
    const int nrows = in_sizes[0] / KDIM;

    // -------- host: closed-form gamma amplitude scale C (data-independent) ---
    const double dt = 0.01, twopi = 6.283185307179586476925286766559;
    double fd[4], ft[8], pht[8];
    for (int i = 0; i < 4; ++i) fd[i] = 1.0 + 3.0 * (double)i / 3.0;   // 1..4
    for (int i = 0; i < 8; ++i) { ft[i] = 4.0 + 4.0 * (double)i / 7.0; pht[i] = 0.0; }
    double Csum = 0.0;
    for (int k = 0; k < 5; ++k) {
        double s = 0.0, c = 0.0;
        for (int i = 0; i < 4; ++i) { double p = twopi * fd[i] * dt * (double)k; s += sin(p); c += cos(p); }
        double mpd = atan2(s * 0.25, c * 0.25);
        double s2 = 0.0, c2 = 0.0;
        for (int i = 0; i < 8; ++i) { s2 += sin(pht[i]); c2 += cos(pht[i]); }
        double mpt = atan2(s2 * 0.125, c2 * 0.125);
        double pac = 1.0 + 0.3 * cos(mpt);
        Csum += pac * pow(1.0 - dt, 4.0 - (double)k);
        for (int i = 0; i < 8; ++i)
            pht[i] += dt * (twopi * ft[i] + 2.0 * sin(mpd - pht[i]));
    }
    const double Cd = pow(1.0 - dt, 5.0) + dt * Csum;
    const float C = (float)Cd;

    hc_prep<<<23, 256, 0, stream>>>(Wd, Wt, Wg, Wc, C, (float*)d_ws);
    hc_main<<<2048, 256, 0, stream>>>(x, (const float*)d_ws, bc, out, nrows);
}